// Round 6
// baseline (461.046 us; speedup 1.0000x reference)
//
#include <hip/hip_runtime.h>

#define LN_EPS 1e-5f

typedef __attribute__((ext_vector_type(8)))  short short8;
typedef __attribute__((ext_vector_type(4)))  short short4v;
typedef __attribute__((ext_vector_type(4)))  float floatx4;
typedef __attribute__((ext_vector_type(16))) float floatx16;

__device__ __forceinline__ unsigned short f2bf(float x) {
    unsigned u = __float_as_uint(x);
    u += 0x7FFFu + ((u >> 16) & 1u);   // round-to-nearest-even
    return (unsigned short)(u >> 16);
}

// ---------------------------------------------------------------------------
// Kernel A: per-edge MLP coords(E,3) -> h(E,32) stored as 32x32x16 B-frags,
// plus per-node integer counts.
// B-frag (K-step t, 32-edge tile et): lane l holds col e = l&31,
// k = t*16 + (l>>5)*8 + b.  short8 idx = et*128 + t*64 + kg*32 + (e&31).
// ---------------------------------------------------------------------------
__global__ __launch_bounds__(256) void k_edge_mlp(
    const float* __restrict__ coords,
    const int*   __restrict__ target,
    const float* __restrict__ W0, const float* __restrict__ b0,
    const float* __restrict__ g0, const float* __restrict__ be0,
    const float* __restrict__ W1, const float* __restrict__ b1,
    const float* __restrict__ g1, const float* __restrict__ be1,
    unsigned short* __restrict__ hfrag, int* __restrict__ counts, int E)
{
    __shared__ float sW0[3*32], sW1[32*32];
    __shared__ float sb0[32], sg0[32], sbe0[32], sb1[32], sg1[32], sbe1[32];
    const int tid = threadIdx.x;
    for (int i = tid; i < 32*32; i += 256) sW1[i] = W1[i];
    if (tid < 96) sW0[tid] = W0[tid];
    if (tid < 32) {
        sb0[tid] = b0[tid];  sg0[tid] = g0[tid];  sbe0[tid] = be0[tid];
        sb1[tid] = b1[tid];  sg1[tid] = g1[tid];  sbe1[tid] = be1[tid];
    }
    __syncthreads();

    const int e = blockIdx.x * 256 + tid;
    if (e >= E) return;

    const float x0 = coords[e*3+0];
    const float x1 = coords[e*3+1];
    const float x2 = coords[e*3+2];

    float h[32];
    #pragma unroll
    for (int o = 0; o < 32; ++o)
        h[o] = x0*sW0[o] + x1*sW0[32+o] + x2*sW0[64+o] + sb0[o];

    {
        float mu = 0.f;
        #pragma unroll
        for (int o = 0; o < 32; ++o) mu += h[o];
        mu *= (1.f/32.f);
        float var = 0.f;
        #pragma unroll
        for (int o = 0; o < 32; ++o) { float d = h[o]-mu; var += d*d; }
        var *= (1.f/32.f);
        const float inv = rsqrtf(var + LN_EPS);
        #pragma unroll
        for (int o = 0; o < 32; ++o)
            h[o] = fmaxf((h[o]-mu)*inv*sg0[o] + sbe0[o], 0.f);
    }

    float h2[32];
    #pragma unroll
    for (int o = 0; o < 32; ++o) {
        float s = sb1[o];
        #pragma unroll
        for (int c = 0; c < 32; ++c) s += h[c]*sW1[c*32+o];
        h2[o] = s;
    }

    {
        float mu = 0.f;
        #pragma unroll
        for (int o = 0; o < 32; ++o) mu += h2[o];
        mu *= (1.f/32.f);
        float var = 0.f;
        #pragma unroll
        for (int o = 0; o < 32; ++o) { float d = h2[o]-mu; var += d*d; }
        var *= (1.f/32.f);
        const float inv = rsqrtf(var + LN_EPS);
        #pragma unroll
        for (int o = 0; o < 32; ++o)
            h2[o] = fmaxf((h2[o]-mu)*inv*sg1[o] + sbe1[o], 0.f);
    }

    const int et = e >> 5, er = e & 31;
    short8* base = (short8*)(hfrag) + (size_t)et * 128;
    #pragma unroll
    for (int t = 0; t < 2; ++t) {
        #pragma unroll
        for (int kg = 0; kg < 2; ++kg) {
            short8 v;
            #pragma unroll
            for (int b = 0; b < 8; ++b) v[b] = (short)f2bf(h2[t*16 + kg*8 + b]);
            base[t*64 + kg*32 + er] = v;
        }
    }

    atomicAdd(&counts[target[e]], 1);
}

// ---------------------------------------------------------------------------
// Kernel W2cvt: W2 fp32 [32][1024] -> bf16 A-frags for 32x32x16.
// Frag (o, t): lane l holds row j = o*32 + (l&31), k = t*16 + (l>>5)*8 + b.
// ---------------------------------------------------------------------------
__global__ __launch_bounds__(256) void k_w2cvt(
    const float* __restrict__ W2, unsigned short* __restrict__ w2frag)
{
    const int idx = blockIdx.x * 256 + threadIdx.x;   // 0..4095
    if (idx >= 4096) return;
    const int l  = idx & 63;
    const int ot = idx >> 6;
    const int t  = ot & 1;
    const int o  = ot >> 1;
    const int row = l & 31;
    const int kb  = t*16 + (l >> 5)*8;
    short8 v;
    #pragma unroll
    for (int b = 0; b < 8; ++b)
        v[b] = (short)f2bf(W2[(size_t)(kb + b)*1024 + o*32 + row]);
    ((short8*)w2frag)[idx] = v;
}

// ---------------------------------------------------------------------------
// Kernel scan: exclusive prefix sum of counts[N] -> offs[N+1] and cursor.
// ---------------------------------------------------------------------------
__global__ __launch_bounds__(1024) void k_scan(
    const int* __restrict__ counts, int* __restrict__ offs,
    int* __restrict__ cursor, int N)
{
    __shared__ int wsum[16];
    const int t = threadIdx.x;
    const int lane = t & 63, w = t >> 6;
    const int CH = (N + 1023) >> 10;
    const int beg = t * CH;

    int s = 0;
    for (int k = 0; k < CH; ++k) {
        const int i = beg + k;
        if (i < N) s += counts[i];
    }
    int incl = s;
    #pragma unroll
    for (int d = 1; d < 64; d <<= 1) {
        const int x = __shfl_up(incl, d);
        if (lane >= d) incl += x;
    }
    if (lane == 63) wsum[w] = incl;
    __syncthreads();
    if (t == 0) {
        int run = 0;
        #pragma unroll
        for (int i = 0; i < 16; ++i) { const int v = wsum[i]; wsum[i] = run; run += v; }
    }
    __syncthreads();
    const int base = wsum[w] + incl - s;
    int run = base;
    for (int k = 0; k < CH; ++k) {
        const int i = beg + k;
        if (i < N) { offs[i] = run; cursor[i] = run; run += counts[i]; }
    }
    if (t == 1023) offs[N] = base + s;
}

// ---------------------------------------------------------------------------
// Kernel bucket: pos[e] = CSR slot of edge e within its target's bucket.
// ---------------------------------------------------------------------------
__global__ __launch_bounds__(256) void k_bucket(
    const int* __restrict__ tgt, int* __restrict__ cursor,
    int* __restrict__ pos, int E)
{
    const int e = blockIdx.x * 256 + threadIdx.x;
    if (e < E) pos[e] = atomicAdd(&cursor[tgt[e]], 1);
}

// ---------------------------------------------------------------------------
// Kernel B: 32x32x16 MFMA, D = W2T_tile @ h_tile (C = 0).
// Epilogue: t = fma(d, KE, KE*b2) [KE*b2 from LDS]; r = rcp(exp2(t)+1);
//   oc[e,o] = fsum - 2*sum(f*r)  (tanh folded).
// Register-light: W2 A-frags streamed per-u; b2 in LDS; target <=64 VGPR
// so 32 waves/CU (8/SIMD) hide gather/L2 latency.
// ---------------------------------------------------------------------------
__global__ __launch_bounds__(512, 8) void k_field_mfma(
    const unsigned short* __restrict__ hfrag,
    const unsigned short* __restrict__ w2frag,
    const float* __restrict__ features,
    const int*   __restrict__ src,
    const int*   __restrict__ pos,
    const float* __restrict__ b2,
    unsigned short* __restrict__ ocP,
    int netiles)
{
    __shared__ float s_b2s[1024];
    const int tid = threadIdx.x;
    const float KE = 2.8853900817779268f;   // 2*log2(e)
    s_b2s[tid]       = KE * b2[tid];
    s_b2s[tid + 512] = KE * b2[tid + 512];
    __syncthreads();

    const int lane = tid & 63;
    const int w    = tid >> 6;      // 0..7
    const int h5   = lane >> 5;
    const int ecol = lane & 31;
    const float* b2base = &s_b2s[w*128 + 4*h5];

    const floatx16 z16 = {0.f,0.f,0.f,0.f,0.f,0.f,0.f,0.f,
                          0.f,0.f,0.f,0.f,0.f,0.f,0.f,0.f};

    for (int et = blockIdx.x; et < netiles; et += gridDim.x) {
        const int e0 = et << 5;
        const short8 bs0 = ((const short8*)hfrag)[et*128 + lane];
        const short8 bs1 = ((const short8*)hfrag)[et*128 + 64 + lane];

        const int sN = src[e0 + ecol];
        const int p  = pos[e0 + ecol];

        floatx4 fv[4];
        float fsl = 0.f;
        #pragma unroll
        for (int rq = 0; rq < 4; ++rq) {
            fv[rq] = *reinterpret_cast<const floatx4*>(
                         features + (size_t)sN*32 + rq*8 + 4*h5);
            #pragma unroll
            for (int rr = 0; rr < 4; ++rr) fsl += fv[rq][rr];
        }

        float q[4];
        #pragma unroll
        for (int u = 0; u < 4; ++u) {
            const short8 a0 = ((const short8*)w2frag)[((w*4+u)*2    )*64 + lane];
            const short8 a1 = ((const short8*)w2frag)[((w*4+u)*2 + 1)*64 + lane];
            floatx16 d = __builtin_amdgcn_mfma_f32_32x32x16_bf16(a0, bs0, z16, 0, 0, 0);
            d          = __builtin_amdgcn_mfma_f32_32x32x16_bf16(a1, bs1, d,   0, 0, 0);
            float sf = 0.f;
            #pragma unroll
            for (int qq = 0; qq < 4; ++qq) {
                const floatx4 bq = *reinterpret_cast<const floatx4*>(b2base + u*32 + 8*qq);
                #pragma unroll
                for (int i = 0; i < 4; ++i) {
                    const float t = fmaf(d[qq*4 + i], KE, bq[i]);
                    const float r = __builtin_amdgcn_rcpf(__builtin_amdgcn_exp2f(t) + 1.0f);
                    sf = fmaf(fv[qq][i], r, sf);
                }
            }
            const float v = fmaf(-2.0f, sf, fsl);   // lane-half of fsum - 2*sum(f*r)
            q[u] = v + __shfl_xor(v, 32);
        }

        if (lane < 32) {
            short4v vv;
            #pragma unroll
            for (int u = 0; u < 4; ++u) vv[u] = (short)f2bf(q[u]);
            *reinterpret_cast<short4v*>(ocP + (size_t)p*32 + w*4) = vv;
        }
    }
}

// ---------------------------------------------------------------------------
// Kernel gather: CSR rows of ocP (target-sorted), mean, write out.
// 64 lanes per node: lane = r*8 + c; lane covers row beg+r (+8k), o = c*4..c*4+3.
// dwordx2 loads (8 lanes x 8B = full 64B row), 3 shfl_xor reduce.
// ---------------------------------------------------------------------------
__global__ __launch_bounds__(256) void k_gather(
    const unsigned short* __restrict__ ocP,
    const int* __restrict__ offs,
    float* __restrict__ out, int N)
{
    const int node = blockIdx.x * 4 + (threadIdx.x >> 6);
    const int lane = threadIdx.x & 63;
    if (node >= N) return;
    const int r = lane >> 3;        // 0..7  row stagger
    const int c = lane & 7;         // 0..7  o-chunk (4 shorts)
    const int beg = offs[node], end = offs[node + 1];

    float a0 = 0.f, a1 = 0.f, a2 = 0.f, a3 = 0.f;
    for (int k = beg + r; k < end; k += 8) {
        const uint2 v = *reinterpret_cast<const uint2*>(ocP + (size_t)k*32 + c*4);
        a0 += __uint_as_float(v.x << 16);
        a1 += __uint_as_float(v.x & 0xFFFF0000u);
        a2 += __uint_as_float(v.y << 16);
        a3 += __uint_as_float(v.y & 0xFFFF0000u);
    }
    #pragma unroll
    for (int m = 8; m < 64; m <<= 1) {
        a0 += __shfl_xor(a0, m);
        a1 += __shfl_xor(a1, m);
        a2 += __shfl_xor(a2, m);
        a3 += __shfl_xor(a3, m);
    }
    if (lane < 8) {
        const float rinv = __builtin_amdgcn_rcpf(fmaxf((float)(end - beg), 1.0f));
        floatx4 o4 = {a0*rinv, a1*rinv, a2*rinv, a3*rinv};
        *reinterpret_cast<floatx4*>(out + (size_t)node*32 + lane*4) = o4;
    }
}

// ---------------------------------------------------------------------------
extern "C" void kernel_launch(void* const* d_in, const int* in_sizes, int n_in,
                              void* d_out, int out_size, void* d_ws, size_t ws_size,
                              hipStream_t stream)
{
    const float* features = (const float*)d_in[0];
    const float* coords   = (const float*)d_in[1];
    const int*   src      = (const int*)  d_in[2];
    const int*   tgt      = (const int*)  d_in[3];
    const float* W0  = (const float*)d_in[4];
    const float* b0  = (const float*)d_in[5];
    const float* g0  = (const float*)d_in[6];
    const float* be0 = (const float*)d_in[7];
    const float* W1  = (const float*)d_in[8];
    const float* b1  = (const float*)d_in[9];
    const float* g1  = (const float*)d_in[10];
    const float* be1 = (const float*)d_in[11];
    const float* W2  = (const float*)d_in[12];
    const float* b2  = (const float*)d_in[13];

    const int E = in_sizes[2];           // 160000 (multiple of 32)
    const int N = in_sizes[0] / 32;      // 10000

    char* p = (char*)d_ws;
    unsigned short* hfrag  = (unsigned short*)p;  p += (size_t)E*32*2;   // 10.24 MB
    unsigned short* ocP    = (unsigned short*)p;  p += (size_t)E*32*2;   // 10.24 MB
    unsigned short* w2frag = (unsigned short*)p;  p += 32*1024*2;        // 64 KB
    int* posArr = (int*)p;  p += (size_t)E*4;                            // 640 KB
    int* counts = (int*)p;  p += (size_t)N*4;
    int* cursor = (int*)p;  p += (size_t)N*4;
    int* offs   = (int*)p;  p += (size_t)(N+1)*4;

    (void)hipMemsetAsync(counts, 0, (size_t)N*4, stream);

    k_edge_mlp<<<(E + 255)/256, 256, 0, stream>>>(
        coords, tgt, W0, b0, g0, be0, W1, b1, g1, be1, hfrag, counts, E);

    k_w2cvt<<<16, 256, 0, stream>>>(W2, w2frag);

    k_scan<<<1, 1024, 0, stream>>>(counts, offs, cursor, N);

    k_bucket<<<(E + 255)/256, 256, 0, stream>>>(tgt, cursor, posArr, E);

    const int netiles = E / 32;          // 5000
    k_field_mfma<<<1024, 512, 0, stream>>>(
        hfrag, w2frag, features, src, posArr, b2, ocP, netiles);

    k_gather<<<(N + 3)/4, 256, 0, stream>>>(ocP, offs, (float*)d_out, N);
}

// Round 7
// 203.011 us; speedup vs baseline: 2.2710x; 2.2710x over previous
//
#include <hip/hip_runtime.h>

#define LN_EPS 1e-5f

typedef __attribute__((ext_vector_type(8)))  short short8;
typedef __attribute__((ext_vector_type(4)))  short short4v;
typedef __attribute__((ext_vector_type(4)))  float floatx4;
typedef __attribute__((ext_vector_type(16))) float floatx16;

__device__ __forceinline__ unsigned short f2bf(float x) {
    unsigned u = __float_as_uint(x);
    u += 0x7FFFu + ((u >> 16) & 1u);   // round-to-nearest-even
    return (unsigned short)(u >> 16);
}

// ---------------------------------------------------------------------------
// Kernel A (fused): blocks [0, nEB): per-edge MLP coords -> h B-frags + counts.
//                   blocks [nEB, nEB+16): W2 fp32 -> bf16 A-frags.
// B-frag (K-step t, 32-edge tile et): lane l holds col e = l&31,
// k = t*16 + (l>>5)*8 + b.  short8 idx = et*128 + t*64 + kg*32 + (e&31).
// A-frag (o, t): lane l holds row j = o*32 + (l&31), k = t*16 + (l>>5)*8 + b.
// ---------------------------------------------------------------------------
__global__ __launch_bounds__(256) void k_edge_mlp(
    const float* __restrict__ coords,
    const int*   __restrict__ target,
    const float* __restrict__ W0, const float* __restrict__ b0,
    const float* __restrict__ g0, const float* __restrict__ be0,
    const float* __restrict__ W1, const float* __restrict__ b1,
    const float* __restrict__ g1, const float* __restrict__ be1,
    const float* __restrict__ W2, unsigned short* __restrict__ w2frag,
    unsigned short* __restrict__ hfrag, int* __restrict__ counts,
    int E, int nEB)
{
    const int tid = threadIdx.x;

    if (blockIdx.x >= nEB) {            // ---- W2 converter blocks ----
        const int idx = (blockIdx.x - nEB) * 256 + tid;   // 0..4095
        if (idx < 4096) {
            const int l  = idx & 63;
            const int ot = idx >> 6;
            const int t  = ot & 1;
            const int o  = ot >> 1;
            const int row = l & 31;
            const int kb  = t*16 + (l >> 5)*8;
            short8 v;
            #pragma unroll
            for (int b = 0; b < 8; ++b)
                v[b] = (short)f2bf(W2[(size_t)(kb + b)*1024 + o*32 + row]);
            ((short8*)w2frag)[idx] = v;
        }
        return;
    }

    __shared__ float sW0[3*32], sW1[32*32];
    __shared__ float sb0[32], sg0[32], sbe0[32], sb1[32], sg1[32], sbe1[32];
    for (int i = tid; i < 32*32; i += 256) sW1[i] = W1[i];
    if (tid < 96) sW0[tid] = W0[tid];
    if (tid < 32) {
        sb0[tid] = b0[tid];  sg0[tid] = g0[tid];  sbe0[tid] = be0[tid];
        sb1[tid] = b1[tid];  sg1[tid] = g1[tid];  sbe1[tid] = be1[tid];
    }
    __syncthreads();

    const int e = blockIdx.x * 256 + tid;
    if (e >= E) return;

    const float x0 = coords[e*3+0];
    const float x1 = coords[e*3+1];
    const float x2 = coords[e*3+2];

    float h[32];
    #pragma unroll
    for (int o = 0; o < 32; ++o)
        h[o] = x0*sW0[o] + x1*sW0[32+o] + x2*sW0[64+o] + sb0[o];

    {
        float mu = 0.f;
        #pragma unroll
        for (int o = 0; o < 32; ++o) mu += h[o];
        mu *= (1.f/32.f);
        float var = 0.f;
        #pragma unroll
        for (int o = 0; o < 32; ++o) { float d = h[o]-mu; var += d*d; }
        var *= (1.f/32.f);
        const float inv = rsqrtf(var + LN_EPS);
        #pragma unroll
        for (int o = 0; o < 32; ++o)
            h[o] = fmaxf((h[o]-mu)*inv*sg0[o] + sbe0[o], 0.f);
    }

    float h2[32];
    #pragma unroll
    for (int o = 0; o < 32; ++o) {
        float s = sb1[o];
        #pragma unroll
        for (int c = 0; c < 32; ++c) s += h[c]*sW1[c*32+o];
        h2[o] = s;
    }

    {
        float mu = 0.f;
        #pragma unroll
        for (int o = 0; o < 32; ++o) mu += h2[o];
        mu *= (1.f/32.f);
        float var = 0.f;
        #pragma unroll
        for (int o = 0; o < 32; ++o) { float d = h2[o]-mu; var += d*d; }
        var *= (1.f/32.f);
        const float inv = rsqrtf(var + LN_EPS);
        #pragma unroll
        for (int o = 0; o < 32; ++o)
            h2[o] = fmaxf((h2[o]-mu)*inv*sg1[o] + sbe1[o], 0.f);
    }

    const int et = e >> 5, er = e & 31;
    short8* base = (short8*)(hfrag) + (size_t)et * 128;
    #pragma unroll
    for (int t = 0; t < 2; ++t) {
        #pragma unroll
        for (int kg = 0; kg < 2; ++kg) {
            short8 v;
            #pragma unroll
            for (int b = 0; b < 8; ++b) v[b] = (short)f2bf(h2[t*16 + kg*8 + b]);
            base[t*64 + kg*32 + er] = v;
        }
    }

    atomicAdd(&counts[target[e]], 1);
}

// ---------------------------------------------------------------------------
// Kernel scan: exclusive prefix sum of counts[N] -> offs[N+1] and cursor.
// ---------------------------------------------------------------------------
__global__ __launch_bounds__(1024) void k_scan(
    const int* __restrict__ counts, int* __restrict__ offs,
    int* __restrict__ cursor, int N)
{
    __shared__ int wsum[16];
    const int t = threadIdx.x;
    const int lane = t & 63, w = t >> 6;
    const int CH = (N + 1023) >> 10;
    const int beg = t * CH;

    int s = 0;
    for (int k = 0; k < CH; ++k) {
        const int i = beg + k;
        if (i < N) s += counts[i];
    }
    int incl = s;
    #pragma unroll
    for (int d = 1; d < 64; d <<= 1) {
        const int x = __shfl_up(incl, d);
        if (lane >= d) incl += x;
    }
    if (lane == 63) wsum[w] = incl;
    __syncthreads();
    if (t == 0) {
        int run = 0;
        #pragma unroll
        for (int i = 0; i < 16; ++i) { const int v = wsum[i]; wsum[i] = run; run += v; }
    }
    __syncthreads();
    const int base = wsum[w] + incl - s;
    int run = base;
    for (int k = 0; k < CH; ++k) {
        const int i = beg + k;
        if (i < N) { offs[i] = run; cursor[i] = run; run += counts[i]; }
    }
    if (t == 1023) offs[N] = base + s;
}

// ---------------------------------------------------------------------------
// Kernel bucket: pos[e] = CSR slot of edge e within its target's bucket.
// ---------------------------------------------------------------------------
__global__ __launch_bounds__(256) void k_bucket(
    const int* __restrict__ tgt, int* __restrict__ cursor,
    int* __restrict__ pos, int E)
{
    const int e = blockIdx.x * 256 + threadIdx.x;
    if (e < E) pos[e] = atomicAdd(&cursor[tgt[e]], 1);
}

// ---------------------------------------------------------------------------
// Kernel B: 32x32x16 MFMA, D = W2T_tile @ h_tile (C = 0).
// Epilogue: t = fma(d, KE, KE*b2) [KE*b2 from LDS]; r = rcp(exp2(t)+1);
//   oc[e,o] = fsum - 2*sum(f*r)  (tanh folded).
// b2 in LDS; W2 A-frags streamed per-u from L2. Natural VGPR (~80-90, no
// spill) at 4 waves/SIMD min — round 6 proved forcing 8 spills everything.
// ---------------------------------------------------------------------------
__global__ __launch_bounds__(512, 4) void k_field_mfma(
    const unsigned short* __restrict__ hfrag,
    const unsigned short* __restrict__ w2frag,
    const float* __restrict__ features,
    const int*   __restrict__ src,
    const int*   __restrict__ pos,
    const float* __restrict__ b2,
    unsigned short* __restrict__ ocP,
    int netiles)
{
    __shared__ float s_b2s[1024];
    const int tid = threadIdx.x;
    const float KE = 2.8853900817779268f;   // 2*log2(e)
    s_b2s[tid]       = KE * b2[tid];
    s_b2s[tid + 512] = KE * b2[tid + 512];
    __syncthreads();

    const int lane = tid & 63;
    const int w    = tid >> 6;      // 0..7
    const int h5   = lane >> 5;
    const int ecol = lane & 31;
    const float* b2base = &s_b2s[w*128 + 4*h5];

    const floatx16 z16 = {0.f,0.f,0.f,0.f,0.f,0.f,0.f,0.f,
                          0.f,0.f,0.f,0.f,0.f,0.f,0.f,0.f};

    for (int et = blockIdx.x; et < netiles; et += gridDim.x) {
        const int e0 = et << 5;
        const short8 bs0 = ((const short8*)hfrag)[et*128 + lane];
        const short8 bs1 = ((const short8*)hfrag)[et*128 + 64 + lane];

        const int sN = src[e0 + ecol];
        const int p  = pos[e0 + ecol];

        floatx4 fv[4];
        float fsl = 0.f;
        #pragma unroll
        for (int rq = 0; rq < 4; ++rq) {
            fv[rq] = *reinterpret_cast<const floatx4*>(
                         features + (size_t)sN*32 + rq*8 + 4*h5);
            #pragma unroll
            for (int rr = 0; rr < 4; ++rr) fsl += fv[rq][rr];
        }

        float q[4];
        #pragma unroll
        for (int u = 0; u < 4; ++u) {
            const short8 a0 = ((const short8*)w2frag)[((w*4+u)*2    )*64 + lane];
            const short8 a1 = ((const short8*)w2frag)[((w*4+u)*2 + 1)*64 + lane];
            floatx16 d = __builtin_amdgcn_mfma_f32_32x32x16_bf16(a0, bs0, z16, 0, 0, 0);
            d          = __builtin_amdgcn_mfma_f32_32x32x16_bf16(a1, bs1, d,   0, 0, 0);
            float sf = 0.f;
            #pragma unroll
            for (int qq = 0; qq < 4; ++qq) {
                const floatx4 bq = *reinterpret_cast<const floatx4*>(b2base + u*32 + 8*qq);
                #pragma unroll
                for (int i = 0; i < 4; ++i) {
                    const float t = fmaf(d[qq*4 + i], KE, bq[i]);
                    const float r = __builtin_amdgcn_rcpf(__builtin_amdgcn_exp2f(t) + 1.0f);
                    sf = fmaf(fv[qq][i], r, sf);
                }
            }
            const float v = fmaf(-2.0f, sf, fsl);   // lane-half of fsum - 2*sum(f*r)
            q[u] = v + __shfl_xor(v, 32);
        }

        if (lane < 32) {
            short4v vv;
            #pragma unroll
            for (int u = 0; u < 4; ++u) vv[u] = (short)f2bf(q[u]);
            *reinterpret_cast<short4v*>(ocP + (size_t)p*32 + w*4) = vv;
        }
    }
}

// ---------------------------------------------------------------------------
// Kernel gather: CSR rows of ocP (target-sorted), mean, write out.
// 64 lanes per node: lane = r*8 + c; row beg+r (+8k), o-chunk c (4 shorts).
// ---------------------------------------------------------------------------
__global__ __launch_bounds__(256) void k_gather(
    const unsigned short* __restrict__ ocP,
    const int* __restrict__ offs,
    float* __restrict__ out, int N)
{
    const int node = blockIdx.x * 4 + (threadIdx.x >> 6);
    const int lane = threadIdx.x & 63;
    if (node >= N) return;
    const int r = lane >> 3;        // 0..7  row stagger
    const int c = lane & 7;         // 0..7  o-chunk (4 shorts)
    const int beg = offs[node], end = offs[node + 1];

    float a0 = 0.f, a1 = 0.f, a2 = 0.f, a3 = 0.f;
    for (int k = beg + r; k < end; k += 8) {
        const uint2 v = *reinterpret_cast<const uint2*>(ocP + (size_t)k*32 + c*4);
        a0 += __uint_as_float(v.x << 16);
        a1 += __uint_as_float(v.x & 0xFFFF0000u);
        a2 += __uint_as_float(v.y << 16);
        a3 += __uint_as_float(v.y & 0xFFFF0000u);
    }
    #pragma unroll
    for (int m = 8; m < 64; m <<= 1) {
        a0 += __shfl_xor(a0, m);
        a1 += __shfl_xor(a1, m);
        a2 += __shfl_xor(a2, m);
        a3 += __shfl_xor(a3, m);
    }
    if (lane < 8) {
        const float rinv = __builtin_amdgcn_rcpf(fmaxf((float)(end - beg), 1.0f));
        floatx4 o4 = {a0*rinv, a1*rinv, a2*rinv, a3*rinv};
        *reinterpret_cast<floatx4*>(out + (size_t)node*32 + lane*4) = o4;
    }
}

// ---------------------------------------------------------------------------
extern "C" void kernel_launch(void* const* d_in, const int* in_sizes, int n_in,
                              void* d_out, int out_size, void* d_ws, size_t ws_size,
                              hipStream_t stream)
{
    const float* features = (const float*)d_in[0];
    const float* coords   = (const float*)d_in[1];
    const int*   src      = (const int*)  d_in[2];
    const int*   tgt      = (const int*)  d_in[3];
    const float* W0  = (const float*)d_in[4];
    const float* b0  = (const float*)d_in[5];
    const float* g0  = (const float*)d_in[6];
    const float* be0 = (const float*)d_in[7];
    const float* W1  = (const float*)d_in[8];
    const float* b1  = (const float*)d_in[9];
    const float* g1  = (const float*)d_in[10];
    const float* be1 = (const float*)d_in[11];
    const float* W2  = (const float*)d_in[12];
    const float* b2  = (const float*)d_in[13];

    const int E = in_sizes[2];           // 160000 (multiple of 32)
    const int N = in_sizes[0] / 32;      // 10000

    char* p = (char*)d_ws;
    unsigned short* hfrag  = (unsigned short*)p;  p += (size_t)E*32*2;   // 10.24 MB
    unsigned short* ocP    = (unsigned short*)p;  p += (size_t)E*32*2;   // 10.24 MB
    unsigned short* w2frag = (unsigned short*)p;  p += 32*1024*2;        // 64 KB
    int* posArr = (int*)p;  p += (size_t)E*4;                            // 640 KB
    int* counts = (int*)p;  p += (size_t)N*4;
    int* cursor = (int*)p;  p += (size_t)N*4;
    int* offs   = (int*)p;  p += (size_t)(N+1)*4;

    (void)hipMemsetAsync(counts, 0, (size_t)N*4, stream);

    const int nEB = (E + 255)/256;       // 625 edge blocks + 16 w2 blocks
    k_edge_mlp<<<nEB + 16, 256, 0, stream>>>(
        coords, tgt, W0, b0, g0, be0, W1, b1, g1, be1, W2, w2frag,
        hfrag, counts, E, nEB);

    k_scan<<<1, 1024, 0, stream>>>(counts, offs, cursor, N);

    k_bucket<<<(E + 255)/256, 256, 0, stream>>>(tgt, cursor, posArr, E);

    const int netiles = E / 32;          // 5000
    k_field_mfma<<<1024, 512, 0, stream>>>(
        hfrag, w2frag, features, src, posArr, b2, ocP, netiles);

    k_gather<<<(N + 3)/4, 256, 0, stream>>>(ocP, offs, (float*)d_out, N);
}

// Round 8
// 115.326 us; speedup vs baseline: 3.9977x; 1.7603x over previous
//
#include <hip/hip_runtime.h>

#define LN_EPS 1e-5f

typedef __attribute__((ext_vector_type(8)))  short short8;
typedef __attribute__((ext_vector_type(4)))  float floatx4;
typedef __attribute__((ext_vector_type(16))) float floatx16;

__device__ __forceinline__ unsigned short f2bf(float x) {
    unsigned u = __float_as_uint(x);
    u += 0x7FFFu + ((u >> 16) & 1u);   // round-to-nearest-even
    return (unsigned short)(u >> 16);
}

// ---------------------------------------------------------------------------
// Kernel A (fused): blocks [0, nEB): per-edge MLP coords -> h B-frags + counts.
//                   blocks [nEB, nEB+16): W2 fp32 -> bf16 A-frags.
// B-frag (K-step t, 32-edge tile et): lane l holds col e = l&31,
// k = t*16 + (l>>5)*8 + b.  short8 idx = et*128 + t*64 + kg*32 + (e&31).
// A-frag (o, t): lane l holds row j = o*32 + (l&31), k = t*16 + (l>>5)*8 + b.
// ---------------------------------------------------------------------------
__global__ __launch_bounds__(256) void k_edge_mlp(
    const float* __restrict__ coords,
    const int*   __restrict__ target,
    const float* __restrict__ W0, const float* __restrict__ b0,
    const float* __restrict__ g0, const float* __restrict__ be0,
    const float* __restrict__ W1, const float* __restrict__ b1,
    const float* __restrict__ g1, const float* __restrict__ be1,
    const float* __restrict__ W2, unsigned short* __restrict__ w2frag,
    unsigned short* __restrict__ hfrag, int* __restrict__ counts,
    int E, int nEB)
{
    const int tid = threadIdx.x;

    if (blockIdx.x >= nEB) {            // ---- W2 converter blocks ----
        const int idx = (blockIdx.x - nEB) * 256 + tid;   // 0..4095
        if (idx < 4096) {
            const int l  = idx & 63;
            const int ot = idx >> 6;
            const int t  = ot & 1;
            const int o  = ot >> 1;
            const int row = l & 31;
            const int kb  = t*16 + (l >> 5)*8;
            short8 v;
            #pragma unroll
            for (int b = 0; b < 8; ++b)
                v[b] = (short)f2bf(W2[(size_t)(kb + b)*1024 + o*32 + row]);
            ((short8*)w2frag)[idx] = v;
        }
        return;
    }

    __shared__ float sW0[3*32], sW1[32*32];
    __shared__ float sb0[32], sg0[32], sbe0[32], sb1[32], sg1[32], sbe1[32];
    for (int i = tid; i < 32*32; i += 256) sW1[i] = W1[i];
    if (tid < 96) sW0[tid] = W0[tid];
    if (tid < 32) {
        sb0[tid] = b0[tid];  sg0[tid] = g0[tid];  sbe0[tid] = be0[tid];
        sb1[tid] = b1[tid];  sg1[tid] = g1[tid];  sbe1[tid] = be1[tid];
    }
    __syncthreads();

    const int e = blockIdx.x * 256 + tid;
    if (e >= E) return;

    const float x0 = coords[e*3+0];
    const float x1 = coords[e*3+1];
    const float x2 = coords[e*3+2];

    float h[32];
    #pragma unroll
    for (int o = 0; o < 32; ++o)
        h[o] = x0*sW0[o] + x1*sW0[32+o] + x2*sW0[64+o] + sb0[o];

    {
        float mu = 0.f;
        #pragma unroll
        for (int o = 0; o < 32; ++o) mu += h[o];
        mu *= (1.f/32.f);
        float var = 0.f;
        #pragma unroll
        for (int o = 0; o < 32; ++o) { float d = h[o]-mu; var += d*d; }
        var *= (1.f/32.f);
        const float inv = rsqrtf(var + LN_EPS);
        #pragma unroll
        for (int o = 0; o < 32; ++o)
            h[o] = fmaxf((h[o]-mu)*inv*sg0[o] + sbe0[o], 0.f);
    }

    float h2[32];
    #pragma unroll
    for (int o = 0; o < 32; ++o) {
        float s = sb1[o];
        #pragma unroll
        for (int c = 0; c < 32; ++c) s += h[c]*sW1[c*32+o];
        h2[o] = s;
    }

    {
        float mu = 0.f;
        #pragma unroll
        for (int o = 0; o < 32; ++o) mu += h2[o];
        mu *= (1.f/32.f);
        float var = 0.f;
        #pragma unroll
        for (int o = 0; o < 32; ++o) { float d = h2[o]-mu; var += d*d; }
        var *= (1.f/32.f);
        const float inv = rsqrtf(var + LN_EPS);
        #pragma unroll
        for (int o = 0; o < 32; ++o)
            h2[o] = fmaxf((h2[o]-mu)*inv*sg1[o] + sbe1[o], 0.f);
    }

    const int et = e >> 5, er = e & 31;
    short8* base = (short8*)(hfrag) + (size_t)et * 128;
    #pragma unroll
    for (int t = 0; t < 2; ++t) {
        #pragma unroll
        for (int kg = 0; kg < 2; ++kg) {
            short8 v;
            #pragma unroll
            for (int b = 0; b < 8; ++b) v[b] = (short)f2bf(h2[t*16 + kg*8 + b]);
            base[t*64 + kg*32 + er] = v;
        }
    }

    atomicAdd(&counts[target[e]], 1);
}

// ---------------------------------------------------------------------------
// Kernel scan: exclusive prefix sum of counts[N] -> offs[N+1] and cursor.
// ---------------------------------------------------------------------------
__global__ __launch_bounds__(1024) void k_scan(
    const int* __restrict__ counts, int* __restrict__ offs,
    int* __restrict__ cursor, int N)
{
    __shared__ int wsum[16];
    const int t = threadIdx.x;
    const int lane = t & 63, w = t >> 6;
    const int CH = (N + 1023) >> 10;
    const int beg = t * CH;

    int s = 0;
    for (int k = 0; k < CH; ++k) {
        const int i = beg + k;
        if (i < N) s += counts[i];
    }
    int incl = s;
    #pragma unroll
    for (int d = 1; d < 64; d <<= 1) {
        const int x = __shfl_up(incl, d);
        if (lane >= d) incl += x;
    }
    if (lane == 63) wsum[w] = incl;
    __syncthreads();
    if (t == 0) {
        int run = 0;
        #pragma unroll
        for (int i = 0; i < 16; ++i) { const int v = wsum[i]; wsum[i] = run; run += v; }
    }
    __syncthreads();
    const int base = wsum[w] + incl - s;
    int run = base;
    for (int k = 0; k < CH; ++k) {
        const int i = beg + k;
        if (i < N) { offs[i] = run; cursor[i] = run; run += counts[i]; }
    }
    if (t == 1023) offs[N] = base + s;
}

// ---------------------------------------------------------------------------
// Kernel bucket: pos[e] = CSR slot of edge e within its target's bucket.
// ---------------------------------------------------------------------------
__global__ __launch_bounds__(256) void k_bucket(
    const int* __restrict__ tgt, int* __restrict__ cursor,
    int* __restrict__ pos, int E)
{
    const int e = blockIdx.x * 256 + threadIdx.x;
    if (e < E) pos[e] = atomicAdd(&cursor[tgt[e]], 1);
}

// ---------------------------------------------------------------------------
// Kernel B: 32x32x16 MFMA, D = W2T_tile @ h_tile (C = 0).
// Epilogue: t = fma(d, KE, KE*b2) [LDS]; r = rcp(exp2(t)+1);
//   oc[e,o] = fsum - 2*sum(f*r)  (tanh folded).
// (512,2): VGPR cap 128 (empirical hipcc rule: cap = 256/w at B=512;
// w=3/4/8 gave 84/64/32 and spilled — round 6/7 post-mortems).
// afr resident (32 VGPR), b2 in LDS, oc tile staged in LDS -> 64B row stores.
// ---------------------------------------------------------------------------
__global__ __launch_bounds__(512, 2) void k_field_mfma(
    const unsigned short* __restrict__ hfrag,
    const unsigned short* __restrict__ w2frag,
    const float* __restrict__ features,
    const int*   __restrict__ src,
    const int*   __restrict__ pos,
    const float* __restrict__ b2,
    unsigned short* __restrict__ ocP,
    int netiles)
{
    __shared__ float s_b2s[1024];
    __shared__ unsigned int sOC[32*17];    // 32 rows x 16 dwords, stride 17
    __shared__ int sP[32];
    const int tid = threadIdx.x;
    const float KE = 2.8853900817779268f;   // 2*log2(e)
    s_b2s[tid]       = KE * b2[tid];
    s_b2s[tid + 512] = KE * b2[tid + 512];

    const int lane = tid & 63;
    const int w    = tid >> 6;      // 0..7
    const int h5   = lane >> 5;
    const int ecol = lane & 31;
    const float* b2base = &s_b2s[w*128 + 4*h5];
    const int str = tid >> 4;       // store-pass row 0..31
    const int sti = tid & 15;       // store-pass dword 0..15

    // resident W2 A-frags: 8 x short8 = 32 VGPR
    short8 afr[8];
    #pragma unroll
    for (int u = 0; u < 8; ++u)
        afr[u] = ((const short8*)w2frag)[(w*8 + u)*64 + lane];
    __syncthreads();

    const floatx16 z16 = {0.f,0.f,0.f,0.f,0.f,0.f,0.f,0.f,
                          0.f,0.f,0.f,0.f,0.f,0.f,0.f,0.f};

    for (int et = blockIdx.x; et < netiles; et += gridDim.x) {
        const int e0 = et << 5;
        const short8 bs0 = ((const short8*)hfrag)[et*128 + lane];
        const short8 bs1 = ((const short8*)hfrag)[et*128 + 64 + lane];

        const int sN = src[e0 + ecol];
        const int p  = pos[e0 + ecol];
        if (tid < 32) sP[ecol] = p;

        floatx4 fv[4];
        float fsl = 0.f;
        #pragma unroll
        for (int rq = 0; rq < 4; ++rq) {
            fv[rq] = *reinterpret_cast<const floatx4*>(
                         features + (size_t)sN*32 + rq*8 + 4*h5);
            #pragma unroll
            for (int rr = 0; rr < 4; ++rr) fsl += fv[rq][rr];
        }

        float q[4];
        #pragma unroll
        for (int u = 0; u < 4; ++u) {
            floatx16 d = __builtin_amdgcn_mfma_f32_32x32x16_bf16(afr[2*u],   bs0, z16, 0, 0, 0);
            d          = __builtin_amdgcn_mfma_f32_32x32x16_bf16(afr[2*u+1], bs1, d,   0, 0, 0);
            float sf = 0.f;
            #pragma unroll
            for (int qq = 0; qq < 4; ++qq) {
                const floatx4 bq = *reinterpret_cast<const floatx4*>(b2base + u*32 + 8*qq);
                #pragma unroll
                for (int i = 0; i < 4; ++i) {
                    const float t = fmaf(d[qq*4 + i], KE, bq[i]);
                    const float r = __builtin_amdgcn_rcpf(__builtin_amdgcn_exp2f(t) + 1.0f);
                    sf = fmaf(fv[qq][i], r, sf);
                }
            }
            const float v = fmaf(-2.0f, sf, fsl);   // lane-half of fsum - 2*sum(f*r)
            q[u] = v + __shfl_xor(v, 32);
        }

        if (lane < 32) {
            const unsigned d0 = ((unsigned)f2bf(q[1]) << 16) | f2bf(q[0]);
            const unsigned d1 = ((unsigned)f2bf(q[3]) << 16) | f2bf(q[2]);
            sOC[ecol*17 + w*2]     = d0;
            sOC[ecol*17 + w*2 + 1] = d1;
        }
        __syncthreads();
        // store pass: 16 lanes per row -> one contiguous 64B store per row
        ((unsigned int*)ocP)[(size_t)sP[str]*16 + sti] = sOC[str*17 + sti];
        __syncthreads();
    }
}

// ---------------------------------------------------------------------------
// Kernel gather: CSR rows of ocP (target-sorted), mean, write out.
// 64 lanes per node: lane = r*8 + c; row beg+r (+8k), o-chunk c (4 shorts).
// ---------------------------------------------------------------------------
__global__ __launch_bounds__(256) void k_gather(
    const unsigned short* __restrict__ ocP,
    const int* __restrict__ offs,
    float* __restrict__ out, int N)
{
    const int node = blockIdx.x * 4 + (threadIdx.x >> 6);
    const int lane = threadIdx.x & 63;
    if (node >= N) return;
    const int r = lane >> 3;        // 0..7  row stagger
    const int c = lane & 7;         // 0..7  o-chunk (4 shorts)
    const int beg = offs[node], end = offs[node + 1];

    float a0 = 0.f, a1 = 0.f, a2 = 0.f, a3 = 0.f;
    for (int k = beg + r; k < end; k += 8) {
        const uint2 v = *reinterpret_cast<const uint2*>(ocP + (size_t)k*32 + c*4);
        a0 += __uint_as_float(v.x << 16);
        a1 += __uint_as_float(v.x & 0xFFFF0000u);
        a2 += __uint_as_float(v.y << 16);
        a3 += __uint_as_float(v.y & 0xFFFF0000u);
    }
    #pragma unroll
    for (int m = 8; m < 64; m <<= 1) {
        a0 += __shfl_xor(a0, m);
        a1 += __shfl_xor(a1, m);
        a2 += __shfl_xor(a2, m);
        a3 += __shfl_xor(a3, m);
    }
    if (lane < 8) {
        const float rinv = __builtin_amdgcn_rcpf(fmaxf((float)(end - beg), 1.0f));
        floatx4 o4 = {a0*rinv, a1*rinv, a2*rinv, a3*rinv};
        *reinterpret_cast<floatx4*>(out + (size_t)node*32 + lane*4) = o4;
    }
}

// ---------------------------------------------------------------------------
extern "C" void kernel_launch(void* const* d_in, const int* in_sizes, int n_in,
                              void* d_out, int out_size, void* d_ws, size_t ws_size,
                              hipStream_t stream)
{
    const float* features = (const float*)d_in[0];
    const float* coords   = (const float*)d_in[1];
    const int*   src      = (const int*)  d_in[2];
    const int*   tgt      = (const int*)  d_in[3];
    const float* W0  = (const float*)d_in[4];
    const float* b0  = (const float*)d_in[5];
    const float* g0  = (const float*)d_in[6];
    const float* be0 = (const float*)d_in[7];
    const float* W1  = (const float*)d_in[8];
    const float* b1  = (const float*)d_in[9];
    const float* g1  = (const float*)d_in[10];
    const float* be1 = (const float*)d_in[11];
    const float* W2  = (const float*)d_in[12];
    const float* b2  = (const float*)d_in[13];

    const int E = in_sizes[2];           // 160000 (multiple of 32)
    const int N = in_sizes[0] / 32;      // 10000

    char* p = (char*)d_ws;
    unsigned short* hfrag  = (unsigned short*)p;  p += (size_t)E*32*2;   // 10.24 MB
    unsigned short* ocP    = (unsigned short*)p;  p += (size_t)E*32*2;   // 10.24 MB
    unsigned short* w2frag = (unsigned short*)p;  p += 32*1024*2;        // 64 KB
    int* posArr = (int*)p;  p += (size_t)E*4;                            // 640 KB
    int* counts = (int*)p;  p += (size_t)N*4;
    int* cursor = (int*)p;  p += (size_t)N*4;
    int* offs   = (int*)p;  p += (size_t)(N+1)*4;

    (void)hipMemsetAsync(counts, 0, (size_t)N*4, stream);

    const int nEB = (E + 255)/256;       // 625 edge blocks + 16 w2 blocks
    k_edge_mlp<<<nEB + 16, 256, 0, stream>>>(
        coords, tgt, W0, b0, g0, be0, W1, b1, g1, be1, W2, w2frag,
        hfrag, counts, E, nEB);

    k_scan<<<1, 1024, 0, stream>>>(counts, offs, cursor, N);

    k_bucket<<<(E + 255)/256, 256, 0, stream>>>(tgt, cursor, posArr, E);

    const int netiles = E / 32;          // 5000
    k_field_mfma<<<1024, 512, 0, stream>>>(
        hfrag, w2frag, features, src, posArr, b2, ocP, netiles);

    k_gather<<<(N + 3)/4, 256, 0, stream>>>(ocP, offs, (float*)d_out, N);
}